// Round 2
// baseline (270.671 us; speedup 1.0000x reference)
//
#include <hip/hip_runtime.h>
#include <math.h>

// Problem constants
#define N_TOK 16384
#define DDIM  2048
#define NE    64
#define TK    8
#define BT    64          // tokens per block (4 waves x 16)
#define NSTEP (DDIM / 32) // 64 K-steps of 32

// Output layout (flat concat, all fp32)
constexpr size_t OFF_TOP  = 0;
constexpr size_t OFF_SC   = (size_t)N_TOK * TK;
constexpr size_t OFF_IDX  = OFF_SC + (size_t)N_TOK * NE;
constexpr size_t OFF_HIST = OFF_IDX + (size_t)N_TOK * TK;
constexpr size_t OFF_ENT  = OFF_HIST + NE;

#define WLVL (NE * DDIM)  // 131072 bf16 elements per split level

typedef short bf16x8 __attribute__((ext_vector_type(8)));
typedef float f32x4  __attribute__((ext_vector_type(4)));

// 3-way bf16 split by truncation: x = hi + mid + lo + O(2^-24 |x|),
// residuals x-hi and x-hi-mid are exact in fp32 (top-16-bit removal).
__device__ __forceinline__ void split3(float x, unsigned short& h,
                                       unsigned short& m, unsigned short& l) {
    unsigned int u0 = __float_as_uint(x);
    h = (unsigned short)(u0 >> 16);
    float r1 = x - __uint_as_float(u0 & 0xffff0000u);
    unsigned int u1 = __float_as_uint(r1);
    m = (unsigned short)(u1 >> 16);
    float r2 = r1 - __uint_as_float(u1 & 0xffff0000u);
    l = (unsigned short)(__float_as_uint(r2) >> 16);
}

// ---------------------------------------------------------------------------
// Prep: split w into hi/mid/lo bf16 and swizzle into B-fragment-linear layout:
// element (e,k): s=k/32, quad=(k/8)%4, nt=e/16, lane=quad*16+(e%16), j=k%8
// offset = ((s*4+nt)*64 + lane)*8 + j   -> each wave B-frag load is one
// contiguous 16B dwordx4 per lane, 1KB contiguous per fragment.
// ---------------------------------------------------------------------------
__global__ __launch_bounds__(256)
void prep_w(const float* __restrict__ w, unsigned short* __restrict__ wre) {
    int gid = blockIdx.x * 256 + threadIdx.x;   // 16384 threads, 8 elems each
    int e  = gid >> 8;
    int kb = gid & 255;
    int k  = kb * 8;
    const float* wp = w + (size_t)e * DDIM + k;
    float4 f0 = *(const float4*)(wp);
    float4 f1 = *(const float4*)(wp + 4);
    float av[8] = {f0.x, f0.y, f0.z, f0.w, f1.x, f1.y, f1.z, f1.w};

    int s = k >> 5, quad = kb & 3, nt = e >> 4, lane = quad * 16 + (e & 15);
    size_t off = ((size_t)(s * 4 + nt) * 64 + lane) * 8;

    unsigned short h[8], m[8], l[8];
    #pragma unroll
    for (int j = 0; j < 8; ++j) split3(av[j], h[j], m[j], l[j]);

    #pragma unroll
    for (int part = 0; part < 3; ++part) {
        const unsigned short* src = (part == 0) ? h : (part == 1) ? m : l;
        uint4 v;
        v.x = (unsigned)src[0] | ((unsigned)src[1] << 16);
        v.y = (unsigned)src[2] | ((unsigned)src[3] << 16);
        v.z = (unsigned)src[4] | ((unsigned)src[5] << 16);
        v.w = (unsigned)src[6] | ((unsigned)src[7] << 16);
        *(uint4*)(wre + (size_t)part * WLVL + off) = v;
    }
}

// ---------------------------------------------------------------------------
// Main fused kernel: barrier-free MFMA K-loop, epilogue sigmoid/top-8/hist/ent
// ---------------------------------------------------------------------------
__global__ __launch_bounds__(256, 1)
void router_mfma(const float* __restrict__ x,
                 const unsigned short* __restrict__ wre,
                 const float* __restrict__ bias,
                 float* __restrict__ out)
{
    __shared__ float sct[NE][BT + 1];   // scores transposed [expert][token]
    __shared__ float bs[NE];
    __shared__ int   hist[NE];

    const int tid  = threadIdx.x;
    const int lane = tid & 63;
    const int wid  = tid >> 6;
    const int t0b  = blockIdx.x * BT;

    if (tid < NE) { bs[tid] = bias[tid]; hist[tid] = 0; }

    const int mrow = lane & 15;     // A-frag token row
    const int quad = lane >> 4;     // A/B-frag k-quad
    const float* xp = x + (size_t)(t0b + wid * 16 + mrow) * DDIM + quad * 8;

    const unsigned short* wh = wre;
    const unsigned short* wm = wre + WLVL;
    const unsigned short* wl = wre + 2 * (size_t)WLVL;
    const size_t lo8 = (size_t)lane * 8;

    f32x4 acc0[4], acc1[4];
    #pragma unroll
    for (int nt = 0; nt < 4; ++nt) {
        acc0[nt] = (f32x4){0.f, 0.f, 0.f, 0.f};
        acc1[nt] = (f32x4){0.f, 0.f, 0.f, 0.f};
    }

    // A prefetch pipeline, depth 2 steps (each step = 2 float4 per lane)
    float4 p0a, p0b, p1a, p1b;
    p0a = *(const float4*)(xp);           p0b = *(const float4*)(xp + 4);
    p1a = *(const float4*)(xp + 32);      p1b = *(const float4*)(xp + 36);

    auto do_step = [&](int s, const float4& fa, const float4& fb, f32x4* acc) {
        // convert A to hi/mid/lo fragments
        float av[8] = {fa.x, fa.y, fa.z, fa.w, fb.x, fb.y, fb.z, fb.w};
        bf16x8 ah, am, al;
        #pragma unroll
        for (int j = 0; j < 8; ++j) {
            unsigned short h, m, l;
            split3(av[j], h, m, l);
            ah[j] = (short)h; am[j] = (short)m; al[j] = (short)l;
        }
        const size_t sb = (size_t)s * 2048 + lo8;   // (s*4+nt)*512 + lane*8
        #pragma unroll
        for (int nt = 0; nt < 4; ++nt) {
            bf16x8 bh = *(const bf16x8*)(wh + sb + nt * 512);
            bf16x8 bm = *(const bf16x8*)(wm + sb + nt * 512);
            bf16x8 bl = *(const bf16x8*)(wl + sb + nt * 512);
            acc[nt] = __builtin_amdgcn_mfma_f32_16x16x32_bf16(ah, bh, acc[nt], 0, 0, 0);
            acc[nt] = __builtin_amdgcn_mfma_f32_16x16x32_bf16(am, bh, acc[nt], 0, 0, 0);
            acc[nt] = __builtin_amdgcn_mfma_f32_16x16x32_bf16(ah, bm, acc[nt], 0, 0, 0);
            acc[nt] = __builtin_amdgcn_mfma_f32_16x16x32_bf16(al, bh, acc[nt], 0, 0, 0);
            acc[nt] = __builtin_amdgcn_mfma_f32_16x16x32_bf16(am, bm, acc[nt], 0, 0, 0);
            acc[nt] = __builtin_amdgcn_mfma_f32_16x16x32_bf16(ah, bl, acc[nt], 0, 0, 0);
        }
    };

    auto run_half = [&](int sbeg, f32x4* acc) {
        for (int s = sbeg; s < sbeg + 32; s += 2) {
            float4 n0a, n0b, n1a, n1b;
            if (s + 2 < NSTEP) {
                n0a = *(const float4*)(xp + (s + 2) * 32);
                n0b = *(const float4*)(xp + (s + 2) * 32 + 4);
                n1a = *(const float4*)(xp + (s + 3) * 32);
                n1b = *(const float4*)(xp + (s + 3) * 32 + 4);
            }
            do_step(s,     p0a, p0b, acc);
            do_step(s + 1, p1a, p1b, acc);
            p0a = n0a; p0b = n0b; p1a = n1a; p1b = n1b;
        }
    };

    run_half(0,  acc0);
    run_half(32, acc1);

    // Epilogue 1: combine K-halves in fp64, sigmoid, scatter scores
    #pragma unroll
    for (int nt = 0; nt < 4; ++nt) {
        const int e = nt * 16 + (lane & 15);
        #pragma unroll
        for (int r = 0; r < 4; ++r) {
            const int trow = quad * 4 + r;          // C/D: row=(lane>>4)*4+reg
            const int tok  = wid * 16 + trow;
            float logit = (float)((double)acc0[nt][r] + (double)acc1[nt][r]);
            float sc = 1.0f / (1.0f + expf(-logit));
            sct[e][tok] = sc;
            out[OFF_SC + (size_t)(t0b + tok) * NE + e] = sc;
        }
    }
    __syncthreads();

    // Epilogue 2: per-token top-8 on wave 0 (register-resident scan)
    if (tid < BT) {
        const int t = tid;
        float v[NE];
        #pragma unroll
        for (int e = 0; e < NE; ++e) v[e] = sct[e][t] + bs[e];

        float chosen[TK];
        int   cidx[TK];
        float ssum = 0.f;
        #pragma unroll
        for (int p = 0; p < TK; ++p) {
            float best = v[0];
            int   bi   = 0;
            #pragma unroll
            for (int e = 1; e < NE; ++e) {   // strict '>' => lowest index on tie
                bool sel = v[e] > best;
                best = sel ? v[e] : best;
                bi   = sel ? e : bi;
            }
            #pragma unroll
            for (int e = 0; e < NE; ++e) v[e] = (e == bi) ? -1e30f : v[e];
            float s = sct[bi][t];            // exact unbiased score
            chosen[p] = s;
            cidx[p]   = bi;
            ssum += s;
            atomicAdd(&hist[bi], 1);
        }

        const float inv = 1.0f / (ssum + 1e-20f);
        float ent = 0.f;
        #pragma unroll
        for (int p = 0; p < TK; ++p) {
            float pn = chosen[p] * inv;      // ROUTE_SCALE == 1.0
            out[OFF_TOP + (size_t)(t0b + t) * TK + p] = pn;
            out[OFF_IDX + (size_t)(t0b + t) * TK + p] = (float)cidx[p];
            ent += pn * logf(pn);
        }
        #pragma unroll
        for (int o = 32; o > 0; o >>= 1) ent += __shfl_down(ent, o);
        if (tid == 0) atomicAdd(&out[OFF_ENT], -ent * (1.0f / (float)N_TOK));
    }
    __syncthreads();

    if (tid < NE) atomicAdd(&out[OFF_HIST + tid], (float)hist[tid]);
}

extern "C" void kernel_launch(void* const* d_in, const int* in_sizes, int n_in,
                              void* d_out, int out_size, void* d_ws, size_t ws_size,
                              hipStream_t stream) {
    const float* x    = (const float*)d_in[0];   // [16384, 2048]
    const float* w    = (const float*)d_in[1];   // [64, 2048]
    const float* bias = (const float*)d_in[2];   // [64]
    float* out = (float*)d_out;
    unsigned short* wre = (unsigned short*)d_ws; // needs 3*131072*2 = 768 KB

    // zero atomic-accumulated outputs (hist + entropy)
    hipMemsetAsync((char*)d_out + OFF_HIST * sizeof(float), 0,
                   (NE + 1) * sizeof(float), stream);

    prep_w<<<dim3(64), dim3(256), 0, stream>>>(w, wre);
    router_mfma<<<dim3(N_TOK / BT), dim3(256), 0, stream>>>(x, wre, bias, out);
}

// Round 4
// 249.803 us; speedup vs baseline: 1.0835x; 1.0835x over previous
//
#include <hip/hip_runtime.h>
#include <math.h>

// Problem constants
#define N_TOK 16384
#define DDIM  2048
#define NE    64
#define TK    8
#define BT    64          // tokens per block tile (4 waves x 16)
#define NKQ   4           // K-split factor
#define KQL   (DDIM / NKQ)    // 512 K per split
#define NSTEP (KQL / 32)      // 16 steps of 32 per split

// Output layout (flat concat, all fp32)
constexpr size_t OFF_TOP  = 0;
constexpr size_t OFF_SC   = (size_t)N_TOK * TK;
constexpr size_t OFF_IDX  = OFF_SC + (size_t)N_TOK * NE;
constexpr size_t OFF_HIST = OFF_IDX + (size_t)N_TOK * TK;
constexpr size_t OFF_ENT  = OFF_HIST + NE;

#define WLVL (NE * DDIM)           // 131072 bf16 per split level
#define PART_OFF_BYTES (1u << 20)  // partial logits at ws + 1 MB (wre = 768 KB)

typedef short bf16x8 __attribute__((ext_vector_type(8)));
typedef float f32x4  __attribute__((ext_vector_type(4)));

// 3-way bf16 split by truncation: x = hi + mid + lo + O(2^-24 |x|)
__device__ __forceinline__ void split3(float x, unsigned short& h,
                                       unsigned short& m, unsigned short& l) {
    unsigned int u0 = __float_as_uint(x);
    h = (unsigned short)(u0 >> 16);
    float r1 = x - __uint_as_float(u0 & 0xffff0000u);
    unsigned int u1 = __float_as_uint(r1);
    m = (unsigned short)(u1 >> 16);
    float r2 = r1 - __uint_as_float(u1 & 0xffff0000u);
    l = (unsigned short)(__float_as_uint(r2) >> 16);
}

// ---------------------------------------------------------------------------
// Prep: split w into hi/mid/lo bf16, swizzled B-fragment-linear:
// offset = ((s*4+nt)*64 + lane)*8 + j,  s=k/32, nt=e/16, lane=(k/8%4)*16+e%16
// ---------------------------------------------------------------------------
__global__ __launch_bounds__(256)
void prep_w(const float* __restrict__ w, unsigned short* __restrict__ wre) {
    int gid = blockIdx.x * 256 + threadIdx.x;   // 16384 threads, 8 elems each
    int e  = gid >> 8;
    int kb = gid & 255;
    int k  = kb * 8;
    const float* wp = w + (size_t)e * DDIM + k;
    float4 f0 = *(const float4*)(wp);
    float4 f1 = *(const float4*)(wp + 4);
    float av[8] = {f0.x, f0.y, f0.z, f0.w, f1.x, f1.y, f1.z, f1.w};

    int s = k >> 5, quad = kb & 3, nt = e >> 4, lane = quad * 16 + (e & 15);
    size_t off = ((size_t)(s * 4 + nt) * 64 + lane) * 8;

    unsigned short h[8], m[8], l[8];
    #pragma unroll
    for (int j = 0; j < 8; ++j) split3(av[j], h[j], m[j], l[j]);

    #pragma unroll
    for (int part = 0; part < 3; ++part) {
        const unsigned short* src = (part == 0) ? h : (part == 1) ? m : l;
        uint4 v;
        v.x = (unsigned)src[0] | ((unsigned)src[1] << 16);
        v.y = (unsigned)src[2] | ((unsigned)src[3] << 16);
        v.z = (unsigned)src[4] | ((unsigned)src[5] << 16);
        v.w = (unsigned)src[6] | ((unsigned)src[7] << 16);
        *(uint4*)(wre + (size_t)part * WLVL + off) = v;
    }
}

// ---------------------------------------------------------------------------
// GEMM: K-split x 4, no LDS, no barriers. 1024 blocks -> 4 blocks/CU.
// Partial fp32 logits -> part[kq][tok][exp]
// ---------------------------------------------------------------------------
__global__ __launch_bounds__(256, 4)
void gemm_part(const float* __restrict__ x,
               const unsigned short* __restrict__ wre,
               float* __restrict__ part)
{
    const int bid  = blockIdx.x;
    const int tile = bid & 255;
    const int kq   = bid >> 8;          // 0..3
    const int tid  = threadIdx.x;
    const int lane = tid & 63;
    const int wid  = tid >> 6;
    const int t0b  = tile * BT;

    const int mrow = lane & 15;
    const int quad = lane >> 4;
    const float* xp = x + (size_t)(t0b + wid * 16 + mrow) * DDIM
                        + kq * KQL + quad * 8;

    const unsigned short* wh = wre;
    const unsigned short* wm = wre + WLVL;
    const unsigned short* wl = wre + 2 * (size_t)WLVL;
    const size_t lo8   = (size_t)lane * 8;
    const size_t sbase = (size_t)(kq * NSTEP) * 2048 + lo8;

    f32x4 acc[4];
    #pragma unroll
    for (int nt = 0; nt < 4; ++nt) acc[nt] = (f32x4){0.f, 0.f, 0.f, 0.f};

    // A pipeline: current step's floats in (ca, cb)
    float4 ca = *(const float4*)(xp);
    float4 cb = *(const float4*)(xp + 4);

    for (int s = 0; s < NSTEP; ++s) {
        // Issue B loads first; A-prefetch after stays in flight longer.
        const size_t sb = sbase + (size_t)s * 2048;
        bf16x8 bh[4], bm[4], bl[4];
        #pragma unroll
        for (int nt = 0; nt < 4; ++nt) {
            bh[nt] = *(const bf16x8*)(wh + sb + nt * 512);
            bm[nt] = *(const bf16x8*)(wm + sb + nt * 512);
            bl[nt] = *(const bf16x8*)(wl + sb + nt * 512);
        }

        // A prefetch for next step (guard tail)
        const int noff = (s + 1 < NSTEP) ? (s + 1) * 32 : 0;
        float4 na = *(const float4*)(xp + noff);
        float4 nb = *(const float4*)(xp + noff + 4);

        // Convert current A to hi/mid/lo bf16 fragments
        float av[8] = {ca.x, ca.y, ca.z, ca.w, cb.x, cb.y, cb.z, cb.w};
        bf16x8 ah, am, al;
        #pragma unroll
        for (int j = 0; j < 8; ++j) {
            unsigned short h, m, l;
            split3(av[j], h, m, l);
            ah[j] = (short)h; am[j] = (short)m; al[j] = (short)l;
        }

        #pragma unroll
        for (int nt = 0; nt < 4; ++nt) {
            acc[nt] = __builtin_amdgcn_mfma_f32_16x16x32_bf16(ah, bh[nt], acc[nt], 0, 0, 0);
            acc[nt] = __builtin_amdgcn_mfma_f32_16x16x32_bf16(am, bh[nt], acc[nt], 0, 0, 0);
            acc[nt] = __builtin_amdgcn_mfma_f32_16x16x32_bf16(ah, bm[nt], acc[nt], 0, 0, 0);
            acc[nt] = __builtin_amdgcn_mfma_f32_16x16x32_bf16(al, bh[nt], acc[nt], 0, 0, 0);
            acc[nt] = __builtin_amdgcn_mfma_f32_16x16x32_bf16(am, bm[nt], acc[nt], 0, 0, 0);
            acc[nt] = __builtin_amdgcn_mfma_f32_16x16x32_bf16(ah, bl[nt], acc[nt], 0, 0, 0);
        }

        ca = na; cb = nb;
    }

    // Store partials: C/D map col=lane&15 (expert), row=quad*4+r (token)
    #pragma unroll
    for (int nt = 0; nt < 4; ++nt) {
        const int e = nt * 16 + mrow;
        #pragma unroll
        for (int r = 0; r < 4; ++r) {
            const int tok = wid * 16 + quad * 4 + r;
            part[((size_t)kq * N_TOK + t0b + tok) * NE + e] = acc[nt][r];
        }
    }
}

// ---------------------------------------------------------------------------
// Epilogue: fp64-combine 4 partials, sigmoid, scores, top-8, hist, entropy
// ---------------------------------------------------------------------------
__global__ __launch_bounds__(256, 2)
void epilogue(const float* __restrict__ part,
              const float* __restrict__ bias,
              float* __restrict__ out)
{
    __shared__ float sct[NE][BT + 1];   // scores transposed [expert][token]
    __shared__ float bs[NE];
    __shared__ int   hist[NE];

    const int tid = threadIdx.x;
    const int t0b = blockIdx.x * BT;

    if (tid < NE) { bs[tid] = bias[tid]; hist[tid] = 0; }

    // Combine + sigmoid. FIXED mapping (round-3 bug covered only 16 tokens):
    // thread -> token tid>>2 (0..63), experts (tid&3)*16 .. +15 (4 float4s).
    {
        const int tok = tid >> 2;          // 0..63  : full BT coverage
        const int e0  = (tid & 3) * 16;    // 0,16,32,48
        #pragma unroll
        for (int g = 0; g < 4; ++g) {
            const int e = e0 + g * 4;
            double d0 = 0, d1 = 0, d2 = 0, d3 = 0;
            #pragma unroll
            for (int kq = 0; kq < NKQ; ++kq) {
                float4 v = *(const float4*)&part[((size_t)kq * N_TOK + t0b + tok) * NE + e];
                d0 += v.x; d1 += v.y; d2 += v.z; d3 += v.w;
            }
            float4 sv;
            sv.x = 1.0f / (1.0f + expf(-(float)d0));
            sv.y = 1.0f / (1.0f + expf(-(float)d1));
            sv.z = 1.0f / (1.0f + expf(-(float)d2));
            sv.w = 1.0f / (1.0f + expf(-(float)d3));
            sct[e + 0][tok] = sv.x;
            sct[e + 1][tok] = sv.y;
            sct[e + 2][tok] = sv.z;
            sct[e + 3][tok] = sv.w;
            *(float4*)&out[OFF_SC + (size_t)(t0b + tok) * NE + e] = sv;
        }
    }
    __syncthreads();

    // Top-8 on wave 0, one token per lane
    if (tid < BT) {
        const int t = tid;
        float v[NE];
        #pragma unroll
        for (int e = 0; e < NE; ++e) v[e] = sct[e][t] + bs[e];

        float chosen[TK];
        int   cidx[TK];
        float ssum = 0.f;
        #pragma unroll
        for (int p = 0; p < TK; ++p) {
            float best = v[0];
            int   bi   = 0;
            #pragma unroll
            for (int e = 1; e < NE; ++e) {   // strict '>' => lowest index on tie
                bool sel = v[e] > best;
                best = sel ? v[e] : best;
                bi   = sel ? e : bi;
            }
            #pragma unroll
            for (int e = 0; e < NE; ++e) v[e] = (e == bi) ? -1e30f : v[e];
            float s = sct[bi][t];
            chosen[p] = s;
            cidx[p]   = bi;
            ssum += s;
            atomicAdd(&hist[bi], 1);
        }

        const float inv = 1.0f / (ssum + 1e-20f);
        float ent = 0.f;
        #pragma unroll
        for (int p = 0; p < TK; ++p) {
            float pn = chosen[p] * inv;      // ROUTE_SCALE == 1.0
            out[OFF_TOP + (size_t)(t0b + t) * TK + p] = pn;
            out[OFF_IDX + (size_t)(t0b + t) * TK + p] = (float)cidx[p];
            ent += pn * logf(pn);
        }
        #pragma unroll
        for (int o = 32; o > 0; o >>= 1) ent += __shfl_down(ent, o);
        if (tid == 0) atomicAdd(&out[OFF_ENT], -ent * (1.0f / (float)N_TOK));
    }
    __syncthreads();

    if (tid < NE) atomicAdd(&out[OFF_HIST + tid], (float)hist[tid]);
}

extern "C" void kernel_launch(void* const* d_in, const int* in_sizes, int n_in,
                              void* d_out, int out_size, void* d_ws, size_t ws_size,
                              hipStream_t stream) {
    const float* x    = (const float*)d_in[0];   // [16384, 2048]
    const float* w    = (const float*)d_in[1];   // [64, 2048]
    const float* bias = (const float*)d_in[2];   // [64]
    float* out = (float*)d_out;
    unsigned short* wre = (unsigned short*)d_ws;                    // 768 KB
    float* part = (float*)((char*)d_ws + PART_OFF_BYTES);           // 16 MB

    // zero atomic-accumulated outputs (hist + entropy)
    hipMemsetAsync((char*)d_out + OFF_HIST * sizeof(float), 0,
                   (NE + 1) * sizeof(float), stream);

    prep_w<<<dim3(64), dim3(256), 0, stream>>>(w, wre);
    gemm_part<<<dim3(256 * NKQ), dim3(256), 0, stream>>>(x, wre, part);
    epilogue<<<dim3(N_TOK / BT), dim3(256), 0, stream>>>(part, bias, out);
}

// Round 5
// 243.512 us; speedup vs baseline: 1.1115x; 1.0258x over previous
//
#include <hip/hip_runtime.h>
#include <math.h>

// Problem constants
#define N_TOK 16384
#define DDIM  2048
#define NE    64
#define TK    8
#define BT    64              // tokens per gemm block tile (4 waves x 16)
#define NKQ   4               // K-split factor
#define KQL   (DDIM / NKQ)    // 512 K per split
#define NSTEP (KQL / 32)      // 16 steps of 32 per split
#define EB    16              // tokens per epilogue block
#define NHC   32              // histogram partial copies

// Output layout (flat concat, all fp32)
constexpr size_t OFF_TOP  = 0;
constexpr size_t OFF_SC   = (size_t)N_TOK * TK;
constexpr size_t OFF_IDX  = OFF_SC + (size_t)N_TOK * NE;
constexpr size_t OFF_HIST = OFF_IDX + (size_t)N_TOK * TK;
constexpr size_t OFF_ENT  = OFF_HIST + NE;

#define WLVL (NE * DDIM)                  // 131072 bf16 per split level
#define PART_OFF  (1u << 20)              // fp32 partials @ ws+1MB (16 MB)
#define HISTP_OFF (PART_OFF + (16u << 20))          // 32*64 ints (8 KB)
#define ENTP_OFF  (HISTP_OFF + NHC * NE * 4)        // 1024 floats (4 KB)

typedef short bf16x8 __attribute__((ext_vector_type(8)));
typedef float f32x4  __attribute__((ext_vector_type(4)));

// 3-way bf16 split by truncation: x = hi + mid + lo + O(2^-24 |x|)
__device__ __forceinline__ void split3(float x, unsigned short& h,
                                       unsigned short& m, unsigned short& l) {
    unsigned int u0 = __float_as_uint(x);
    h = (unsigned short)(u0 >> 16);
    float r1 = x - __uint_as_float(u0 & 0xffff0000u);
    unsigned int u1 = __float_as_uint(r1);
    m = (unsigned short)(u1 >> 16);
    float r2 = r1 - __uint_as_float(u1 & 0xffff0000u);
    l = (unsigned short)(__float_as_uint(r2) >> 16);
}

// ---------------------------------------------------------------------------
// Prep: split w into hi/mid/lo bf16, swizzled B-fragment-linear:
// offset = ((s*4+nt)*64 + lane)*8 + j,  s=k/32, nt=e/16, lane=(k/8%4)*16+e%16
// ---------------------------------------------------------------------------
__global__ __launch_bounds__(256)
void prep_w(const float* __restrict__ w, unsigned short* __restrict__ wre) {
    int gid = blockIdx.x * 256 + threadIdx.x;   // 16384 threads, 8 elems each
    int e  = gid >> 8;
    int kb = gid & 255;
    int k  = kb * 8;
    const float* wp = w + (size_t)e * DDIM + k;
    float4 f0 = *(const float4*)(wp);
    float4 f1 = *(const float4*)(wp + 4);
    float av[8] = {f0.x, f0.y, f0.z, f0.w, f1.x, f1.y, f1.z, f1.w};

    int s = k >> 5, quad = kb & 3, nt = e >> 4, lane = quad * 16 + (e & 15);
    size_t off = ((size_t)(s * 4 + nt) * 64 + lane) * 8;

    unsigned short h[8], m[8], l[8];
    #pragma unroll
    for (int j = 0; j < 8; ++j) split3(av[j], h[j], m[j], l[j]);

    #pragma unroll
    for (int part = 0; part < 3; ++part) {
        const unsigned short* src = (part == 0) ? h : (part == 1) ? m : l;
        uint4 v;
        v.x = (unsigned)src[0] | ((unsigned)src[1] << 16);
        v.y = (unsigned)src[2] | ((unsigned)src[3] << 16);
        v.z = (unsigned)src[4] | ((unsigned)src[5] << 16);
        v.w = (unsigned)src[6] | ((unsigned)src[7] << 16);
        *(uint4*)(wre + (size_t)part * WLVL + off) = v;
    }
}

// ---------------------------------------------------------------------------
// GEMM: K-split x4, no LDS/barriers, REGISTER-DOUBLE-BUFFERED pipeline.
// B (and A) for step s+1 loaded into the alternate buffer at the top of
// step s; consumed one iteration later -> loads stay in flight across a
// full compute body. launch_bounds(256,3): ~170 VGPR budget for ~150 used.
// ---------------------------------------------------------------------------
__global__ __launch_bounds__(256, 3)
void gemm_part(const float* __restrict__ x,
               const unsigned short* __restrict__ wre,
               float* __restrict__ part)
{
    const int bid  = blockIdx.x;
    const int tile = bid & 255;
    const int kq   = bid >> 8;          // 0..3
    const int tid  = threadIdx.x;
    const int lane = tid & 63;
    const int wid  = tid >> 6;
    const int t0b  = tile * BT;

    const int mrow = lane & 15;
    const int quad = lane >> 4;
    const float* xp = x + (size_t)(t0b + wid * 16 + mrow) * DDIM
                        + kq * KQL + quad * 8;
    const unsigned short* wb = wre + (size_t)(kq * NSTEP) * 2048
                                   + (size_t)lane * 8;

    f32x4 acc[4];
    #pragma unroll
    for (int nt = 0; nt < 4; ++nt) acc[nt] = (f32x4){0.f, 0.f, 0.f, 0.f};

    // Double-buffered fragments (indices fold under full unroll)
    bf16x8 Bh[2][4], Bm[2][4], Bl[2][4];
    float4 Aa[2], Ab[2];

    // Preload step 0 into buffer 0
    #pragma unroll
    for (int nt = 0; nt < 4; ++nt) {
        Bh[0][nt] = *(const bf16x8*)(wb + nt * 512);
        Bm[0][nt] = *(const bf16x8*)(wb + WLVL + nt * 512);
        Bl[0][nt] = *(const bf16x8*)(wb + 2 * (size_t)WLVL + nt * 512);
    }
    Aa[0] = *(const float4*)(xp);
    Ab[0] = *(const float4*)(xp + 4);

    #pragma unroll
    for (int s = 0; s < NSTEP; ++s) {
        const int cur = s & 1, nxt = cur ^ 1;

        // Issue next step's loads FIRST (consumed next iteration)
        if (s + 1 < NSTEP) {
            const unsigned short* wn = wb + (size_t)(s + 1) * 2048;
            #pragma unroll
            for (int nt = 0; nt < 4; ++nt) {
                Bh[nxt][nt] = *(const bf16x8*)(wn + nt * 512);
                Bm[nxt][nt] = *(const bf16x8*)(wn + WLVL + nt * 512);
                Bl[nxt][nt] = *(const bf16x8*)(wn + 2 * (size_t)WLVL + nt * 512);
            }
            Aa[nxt] = *(const float4*)(xp + (s + 1) * 32);
            Ab[nxt] = *(const float4*)(xp + (s + 1) * 32 + 4);
        }

        // Split current A into hi/mid/lo bf16 fragments
        float av[8] = {Aa[cur].x, Aa[cur].y, Aa[cur].z, Aa[cur].w,
                       Ab[cur].x, Ab[cur].y, Ab[cur].z, Ab[cur].w};
        bf16x8 ah, am, al;
        #pragma unroll
        for (int j = 0; j < 8; ++j) {
            unsigned short h, m, l;
            split3(av[j], h, m, l);
            ah[j] = (short)h; am[j] = (short)m; al[j] = (short)l;
        }

        #pragma unroll
        for (int nt = 0; nt < 4; ++nt) {
            acc[nt] = __builtin_amdgcn_mfma_f32_16x16x32_bf16(ah, Bh[cur][nt], acc[nt], 0, 0, 0);
            acc[nt] = __builtin_amdgcn_mfma_f32_16x16x32_bf16(am, Bh[cur][nt], acc[nt], 0, 0, 0);
            acc[nt] = __builtin_amdgcn_mfma_f32_16x16x32_bf16(ah, Bm[cur][nt], acc[nt], 0, 0, 0);
            acc[nt] = __builtin_amdgcn_mfma_f32_16x16x32_bf16(al, Bh[cur][nt], acc[nt], 0, 0, 0);
            acc[nt] = __builtin_amdgcn_mfma_f32_16x16x32_bf16(am, Bm[cur][nt], acc[nt], 0, 0, 0);
            acc[nt] = __builtin_amdgcn_mfma_f32_16x16x32_bf16(ah, Bl[cur][nt], acc[nt], 0, 0, 0);
        }
    }

    // Store partials: C/D map col=lane&15 (expert), row=quad*4+r (token)
    #pragma unroll
    for (int nt = 0; nt < 4; ++nt) {
        const int e = nt * 16 + mrow;
        #pragma unroll
        for (int r = 0; r < 4; ++r) {
            const int tok = wid * 16 + quad * 4 + r;
            part[((size_t)kq * N_TOK + t0b + tok) * NE + e] = acc[nt][r];
        }
    }
}

// ---------------------------------------------------------------------------
// Epilogue: 1024 blocks x 16 tokens. fp64-combine, sigmoid, scores, top-8.
// Histogram -> 32 banked int partials in ws; entropy -> per-block partial.
// No float atomics anywhere (deterministic).
// ---------------------------------------------------------------------------
__global__ __launch_bounds__(256, 4)
void epilogue(const float* __restrict__ part,
              const float* __restrict__ bias,
              float* __restrict__ out,
              int* __restrict__ histp,
              float* __restrict__ entp)
{
    __shared__ float sct[NE][EB + 1];   // scores transposed [expert][token]
    __shared__ float bs[NE];
    __shared__ int   hist[NE];

    const int tid = threadIdx.x;
    const int t0b = blockIdx.x * EB;

    if (tid < NE) { bs[tid] = bias[tid]; hist[tid] = 0; }

    // Combine + sigmoid: thread -> token tid>>4 (0..15), experts (tid&15)*4..+3
    {
        const int tok = tid >> 4;
        const int e   = (tid & 15) * 4;
        double d0 = 0, d1 = 0, d2 = 0, d3 = 0;
        #pragma unroll
        for (int kq = 0; kq < NKQ; ++kq) {
            float4 v = *(const float4*)&part[((size_t)kq * N_TOK + t0b + tok) * NE + e];
            d0 += v.x; d1 += v.y; d2 += v.z; d3 += v.w;
        }
        float4 sv;
        sv.x = 1.0f / (1.0f + expf(-(float)d0));
        sv.y = 1.0f / (1.0f + expf(-(float)d1));
        sv.z = 1.0f / (1.0f + expf(-(float)d2));
        sv.w = 1.0f / (1.0f + expf(-(float)d3));
        sct[e + 0][tok] = sv.x;
        sct[e + 1][tok] = sv.y;
        sct[e + 2][tok] = sv.z;
        sct[e + 3][tok] = sv.w;
        *(float4*)&out[OFF_SC + (size_t)(t0b + tok) * NE + e] = sv;
    }
    __syncthreads();

    // Top-8: lanes 0..15 of wave 0, one token each
    float ent = 0.f;
    if (tid < EB) {
        const int t = tid;
        float v[NE];
        #pragma unroll
        for (int e = 0; e < NE; ++e) v[e] = sct[e][t] + bs[e];

        float chosen[TK];
        int   cidx[TK];
        float ssum = 0.f;
        #pragma unroll
        for (int p = 0; p < TK; ++p) {
            float best = v[0];
            int   bi   = 0;
            #pragma unroll
            for (int e = 1; e < NE; ++e) {   // strict '>' => lowest index on tie
                bool sel = v[e] > best;
                best = sel ? v[e] : best;
                bi   = sel ? e : bi;
            }
            #pragma unroll
            for (int e = 0; e < NE; ++e) v[e] = (e == bi) ? -1e30f : v[e];
            float s = sct[bi][t];
            chosen[p] = s;
            cidx[p]   = bi;
            ssum += s;
            atomicAdd(&hist[bi], 1);        // LDS atomic
        }

        const float inv = 1.0f / (ssum + 1e-20f);
        #pragma unroll
        for (int p = 0; p < TK; ++p) {
            float pn = chosen[p] * inv;      // ROUTE_SCALE == 1.0
            out[OFF_TOP + (size_t)(t0b + t) * TK + p] = pn;
            out[OFF_IDX + (size_t)(t0b + t) * TK + p] = (float)cidx[p];
            ent += pn * logf(pn);
        }
    }
    // entropy partial: reduce wave 0 (lanes >=16 hold 0), no atomics
    if (tid < 64) {
        #pragma unroll
        for (int o = 32; o > 0; o >>= 1) ent += __shfl_down(ent, o);
        if (tid == 0) entp[blockIdx.x] = ent;   // sum of pn*log(pn), un-negated
    }
    __syncthreads();

    // banked histogram flush (int atomics, 32-way decontended)
    if (tid < NE && hist[tid] > 0)
        atomicAdd(&histp[(blockIdx.x & (NHC - 1)) * NE + tid], hist[tid]);
}

// ---------------------------------------------------------------------------
// Finalize: reduce histogram banks and entropy partials (deterministic order)
// ---------------------------------------------------------------------------
__global__ __launch_bounds__(256)
void finalize(const int* __restrict__ histp,
              const float* __restrict__ entp,
              float* __restrict__ out)
{
    const int tid = threadIdx.x;
    if (tid < NE) {
        int s = 0;
        #pragma unroll
        for (int c = 0; c < NHC; ++c) s += histp[c * NE + tid];
        out[OFF_HIST + tid] = (float)s;
    }
    __shared__ float red[256];
    float e = 0.f;
    for (int i = tid; i < N_TOK / EB; i += 256) e += entp[i];
    red[tid] = e;
    __syncthreads();
    #pragma unroll
    for (int o = 128; o > 0; o >>= 1) {
        if (tid < o) red[tid] += red[tid + o];
        __syncthreads();
    }
    if (tid == 0) out[OFF_ENT] = -red[0] * (1.0f / (float)N_TOK);
}

extern "C" void kernel_launch(void* const* d_in, const int* in_sizes, int n_in,
                              void* d_out, int out_size, void* d_ws, size_t ws_size,
                              hipStream_t stream) {
    const float* x    = (const float*)d_in[0];   // [16384, 2048]
    const float* w    = (const float*)d_in[1];   // [64, 2048]
    const float* bias = (const float*)d_in[2];   // [64]
    float* out = (float*)d_out;
    unsigned short* wre = (unsigned short*)d_ws;
    float* part  = (float*)((char*)d_ws + PART_OFF);
    int*   histp = (int*)  ((char*)d_ws + HISTP_OFF);
    float* entp  = (float*)((char*)d_ws + ENTP_OFF);

    // zero the banked histogram partials (8 KB)
    hipMemsetAsync(histp, 0, NHC * NE * sizeof(int), stream);

    prep_w   <<<dim3(64),          dim3(256), 0, stream>>>(w, wre);
    gemm_part<<<dim3(256 * NKQ),   dim3(256), 0, stream>>>(x, wre, part);
    epilogue <<<dim3(N_TOK / EB),  dim3(256), 0, stream>>>(part, bias, out, histp, entp);
    finalize <<<dim3(1),           dim3(256), 0, stream>>>(histp, entp, out);
}

// Round 6
// 224.282 us; speedup vs baseline: 1.2068x; 1.0857x over previous
//
#include <hip/hip_runtime.h>
#include <math.h>

// Problem constants
#define N_TOK 16384
#define DDIM  2048
#define NE    64
#define TK    8
#define BT    64              // tokens per gemm block tile (4 waves x 16)
#define NKQ   4               // K-split factor
#define KQL   (DDIM / NKQ)    // 512 K per split
#define NSTEP (KQL / 32)      // 16 steps of 32 per split
#define EB    16              // tokens per epilogue block
#define NHC   32              // histogram partial copies

// Scaling: x*64, w*2048 keeps fp16 split residues in normal range regardless
// of MFMA denormal behavior. Logits come out scaled by 2^17; unscale exactly.
#define XSCALE 64.0f
#define WSCALE 2048.0f
#define LUNSCALE (1.0f / 131072.0f)

// Output layout (flat concat, all fp32)
constexpr size_t OFF_TOP  = 0;
constexpr size_t OFF_SC   = (size_t)N_TOK * TK;
constexpr size_t OFF_IDX  = OFF_SC + (size_t)N_TOK * NE;
constexpr size_t OFF_HIST = OFF_IDX + (size_t)N_TOK * TK;
constexpr size_t OFF_ENT  = OFF_HIST + NE;

#define WLVL (NE * DDIM)                  // 131072 f16 per split level
#define PART_OFF  (1u << 20)              // fp32 partials @ ws+1MB (16 MB)
#define HISTP_OFF (PART_OFF + (16u << 20))
#define ENTP_OFF  (HISTP_OFF + NHC * NE * 4)

typedef _Float16 f16x8 __attribute__((ext_vector_type(8)));
typedef float    f32x4 __attribute__((ext_vector_type(4)));

typedef const __attribute__((address_space(1))) unsigned int gu32;
typedef       __attribute__((address_space(3))) unsigned int lu32;

// 2-level fp16 split: v = h + m + r, |r| <= 2^-22 |v|. v - (float)h is exact.
__device__ __forceinline__ void split2(float v, _Float16& h, _Float16& m) {
    h = (_Float16)v;
    m = (_Float16)(v - (float)h);
}

__device__ __forceinline__ unsigned short f16bits(_Float16 h) {
    union { _Float16 f; unsigned short u; } c; c.f = h; return c.u;
}

// ---------------------------------------------------------------------------
// Prep: w*2048 -> 2-level fp16, swizzled B-fragment-linear:
// offset = ((s*4+nt)*64 + lane)*8 + j,  s=k/32, nt=e/16, lane=(k/8%4)*16+e%16
// ---------------------------------------------------------------------------
__global__ __launch_bounds__(64)
void prep_w(const float* __restrict__ w, unsigned short* __restrict__ wre) {
    int gid = blockIdx.x * 64 + threadIdx.x;   // 16384 threads, 8 elems each
    int e  = gid >> 8;
    int kb = gid & 255;
    int k  = kb * 8;
    const float* wp = w + (size_t)e * DDIM + k;
    float4 f0 = *(const float4*)(wp);
    float4 f1 = *(const float4*)(wp + 4);
    float av[8] = {f0.x, f0.y, f0.z, f0.w, f1.x, f1.y, f1.z, f1.w};

    int s = k >> 5, quad = kb & 3, nt = e >> 4, lane = quad * 16 + (e & 15);
    size_t off = ((size_t)(s * 4 + nt) * 64 + lane) * 8;

    unsigned short hb[8], mb[8];
    #pragma unroll
    for (int j = 0; j < 8; ++j) {
        _Float16 h, m;
        split2(av[j] * WSCALE, h, m);
        hb[j] = f16bits(h); mb[j] = f16bits(m);
    }

    #pragma unroll
    for (int lev = 0; lev < 2; ++lev) {
        const unsigned short* src = lev ? mb : hb;
        uint4 v;
        v.x = (unsigned)src[0] | ((unsigned)src[1] << 16);
        v.y = (unsigned)src[2] | ((unsigned)src[3] << 16);
        v.z = (unsigned)src[4] | ((unsigned)src[5] << 16);
        v.w = (unsigned)src[6] | ((unsigned)src[7] << 16);
        *(uint4*)(wre + (size_t)lev * WLVL + off) = v;
    }
}

// ---------------------------------------------------------------------------
// GEMM: K-split x4, B staged ONCE per block-step into LDS via global_load_lds
// (shared by all 4 waves -> 4x less L2 traffic, the round-5 bottleneck).
// A in registers, depth-2 prefetch. fp16 2-level split, 16 MFMA/step.
// ---------------------------------------------------------------------------
__global__ __launch_bounds__(256, 4)
void gemm_part(const float* __restrict__ x,
               const unsigned short* __restrict__ wre,
               float* __restrict__ part)
{
    // [buf][frag = lev*4+nt][lane*8+j] : 2 * 8 KB = 16 KB
    __shared__ _Float16 Bs[2][8][512];

    const int bid  = blockIdx.x;
    const int tile = bid & 255;
    const int kq   = bid >> 8;          // 0..3
    const int tid  = threadIdx.x;
    const int lane = tid & 63;
    const int wid  = tid >> 6;
    const int t0b  = tile * BT;

    const int mrow = lane & 15;
    const int quad = lane >> 4;
    const float* xp = x + (size_t)(t0b + wid * 16 + mrow) * DDIM
                        + kq * KQL + quad * 8;

    // stage: wave wid stages frags 2*wid and 2*wid+1 (1 KB each, lane x 16B)
    auto stage = [&](int s, int buf) {
        #pragma unroll
        for (int i = 0; i < 2; ++i) {
            const int f = wid * 2 + i, lev = f >> 2, nt = f & 3;
            const unsigned short* g = wre + (size_t)lev * WLVL
                + ((size_t)(kq * NSTEP + s) * 4 + nt) * 512 + (size_t)lane * 8;
            __builtin_amdgcn_global_load_lds((gu32*)g, (lu32*)&Bs[buf][f][0],
                                             16, 0, 0);
        }
    };

    f32x4 acc[4];
    #pragma unroll
    for (int nt = 0; nt < 4; ++nt) acc[nt] = (f32x4){0.f, 0.f, 0.f, 0.f};

    // A prefetch depth 2
    float4 a0a = *(const float4*)(xp),      a0b = *(const float4*)(xp + 4);
    float4 a1a = *(const float4*)(xp + 32), a1b = *(const float4*)(xp + 36);
    float4 a2a, a2b;

    stage(0, 0);
    __syncthreads();

    #pragma unroll
    for (int s = 0; s < NSTEP; ++s) {
        const int cur = s & 1, nxt = cur ^ 1;

        if (s + 1 < NSTEP) stage(s + 1, nxt);
        if (s + 2 < NSTEP) {
            a2a = *(const float4*)(xp + (s + 2) * 32);
            a2b = *(const float4*)(xp + (s + 2) * 32 + 4);
        }

        // B fragments from LDS (shared across waves)
        f16x8 bh[4], bm[4];
        #pragma unroll
        for (int nt = 0; nt < 4; ++nt) {
            bh[nt] = *(const f16x8*)&Bs[cur][nt][lane * 8];
            bm[nt] = *(const f16x8*)&Bs[cur][4 + nt][lane * 8];
        }

        // Convert current A (scaled) to 2-level fp16
        float av[8] = {a0a.x, a0a.y, a0a.z, a0a.w, a0b.x, a0b.y, a0b.z, a0b.w};
        f16x8 ah, am;
        #pragma unroll
        for (int j = 0; j < 8; ++j) {
            _Float16 h, m;
            split2(av[j] * XSCALE, h, m);
            ah[j] = h; am[j] = m;
        }

        #pragma unroll
        for (int nt = 0; nt < 4; ++nt) {
            acc[nt] = __builtin_amdgcn_mfma_f32_16x16x32_f16(ah, bh[nt], acc[nt], 0, 0, 0);
            acc[nt] = __builtin_amdgcn_mfma_f32_16x16x32_f16(am, bh[nt], acc[nt], 0, 0, 0);
            acc[nt] = __builtin_amdgcn_mfma_f32_16x16x32_f16(ah, bm[nt], acc[nt], 0, 0, 0);
            acc[nt] = __builtin_amdgcn_mfma_f32_16x16x32_f16(am, bm[nt], acc[nt], 0, 0, 0);
        }

        __syncthreads();   // staging(nxt) complete; buf(cur) reads done
        a0a = a1a; a0b = a1b; a1a = a2a; a1b = a2b;
    }

    // Store partials: C/D map col=lane&15 (expert), row=quad*4+r (token)
    #pragma unroll
    for (int nt = 0; nt < 4; ++nt) {
        const int e = nt * 16 + mrow;
        #pragma unroll
        for (int r = 0; r < 4; ++r) {
            const int tok = wid * 16 + quad * 4 + r;
            part[((size_t)kq * N_TOK + t0b + tok) * NE + e] = acc[nt][r];
        }
    }
}

// ---------------------------------------------------------------------------
// Epilogue: fp64-combine partials, unscale 2^-17, sigmoid, scores, top-8.
// Histogram -> banked int partials; entropy -> per-block partial. No float
// atomics (deterministic).
// ---------------------------------------------------------------------------
__global__ __launch_bounds__(256, 4)
void epilogue(const float* __restrict__ part,
              const float* __restrict__ bias,
              float* __restrict__ out,
              int* __restrict__ histp,
              float* __restrict__ entp)
{
    __shared__ float sct[NE][EB + 1];
    __shared__ float bs[NE];
    __shared__ int   hist[NE];

    const int tid = threadIdx.x;
    const int t0b = blockIdx.x * EB;

    if (tid < NE) { bs[tid] = bias[tid]; hist[tid] = 0; }

    {
        const int tok = tid >> 4;
        const int e   = (tid & 15) * 4;
        double d0 = 0, d1 = 0, d2 = 0, d3 = 0;
        #pragma unroll
        for (int kq = 0; kq < NKQ; ++kq) {
            float4 v = *(const float4*)&part[((size_t)kq * N_TOK + t0b + tok) * NE + e];
            d0 += v.x; d1 += v.y; d2 += v.z; d3 += v.w;
        }
        float4 sv;
        sv.x = 1.0f / (1.0f + expf(-(float)d0 * LUNSCALE));
        sv.y = 1.0f / (1.0f + expf(-(float)d1 * LUNSCALE));
        sv.z = 1.0f / (1.0f + expf(-(float)d2 * LUNSCALE));
        sv.w = 1.0f / (1.0f + expf(-(float)d3 * LUNSCALE));
        sct[e + 0][tok] = sv.x;
        sct[e + 1][tok] = sv.y;
        sct[e + 2][tok] = sv.z;
        sct[e + 3][tok] = sv.w;
        *(float4*)&out[OFF_SC + (size_t)(t0b + tok) * NE + e] = sv;
    }
    __syncthreads();

    float ent = 0.f;
    if (tid < EB) {
        const int t = tid;
        float v[NE];
        #pragma unroll
        for (int e = 0; e < NE; ++e) v[e] = sct[e][t] + bs[e];

        float chosen[TK];
        int   cidx[TK];
        float ssum = 0.f;
        #pragma unroll
        for (int p = 0; p < TK; ++p) {
            float best = v[0];
            int   bi   = 0;
            #pragma unroll
            for (int e = 1; e < NE; ++e) {   // strict '>' => lowest index on tie
                bool sel = v[e] > best;
                best = sel ? v[e] : best;
                bi   = sel ? e : bi;
            }
            #pragma unroll
            for (int e = 0; e < NE; ++e) v[e] = (e == bi) ? -1e30f : v[e];
            float sc = sct[bi][t];
            chosen[p] = sc;
            cidx[p]   = bi;
            ssum += sc;
            atomicAdd(&hist[bi], 1);        // LDS atomic
        }

        const float inv = 1.0f / (ssum + 1e-20f);
        #pragma unroll
        for (int p = 0; p < TK; ++p) {
            float pn = chosen[p] * inv;      // ROUTE_SCALE == 1.0
            out[OFF_TOP + (size_t)(t0b + t) * TK + p] = pn;
            out[OFF_IDX + (size_t)(t0b + t) * TK + p] = (float)cidx[p];
            ent += pn * logf(pn);
        }
    }
    if (tid < 64) {
        #pragma unroll
        for (int o = 32; o > 0; o >>= 1) ent += __shfl_down(ent, o);
        if (tid == 0) entp[blockIdx.x] = ent;
    }
    __syncthreads();

    if (tid < NE && hist[tid] > 0)
        atomicAdd(&histp[(blockIdx.x & (NHC - 1)) * NE + tid], hist[tid]);
}

// ---------------------------------------------------------------------------
// Finalize: reduce histogram banks and entropy partials (deterministic)
// ---------------------------------------------------------------------------
__global__ __launch_bounds__(256)
void finalize(const int* __restrict__ histp,
              const float* __restrict__ entp,
              float* __restrict__ out)
{
    const int tid = threadIdx.x;
    if (tid < NE) {
        int s = 0;
        #pragma unroll
        for (int c = 0; c < NHC; ++c) s += histp[c * NE + tid];
        out[OFF_HIST + tid] = (float)s;
    }
    __shared__ float red[256];
    float e = 0.f;
    for (int i = tid; i < N_TOK / EB; i += 256) e += entp[i];
    red[tid] = e;
    __syncthreads();
    #pragma unroll
    for (int o = 128; o > 0; o >>= 1) {
        if (tid < o) red[tid] += red[tid + o];
        __syncthreads();
    }
    if (tid == 0) out[OFF_ENT] = -red[0] * (1.0f / (float)N_TOK);
}

extern "C" void kernel_launch(void* const* d_in, const int* in_sizes, int n_in,
                              void* d_out, int out_size, void* d_ws, size_t ws_size,
                              hipStream_t stream) {
    const float* x    = (const float*)d_in[0];   // [16384, 2048]
    const float* w    = (const float*)d_in[1];   // [64, 2048]
    const float* bias = (const float*)d_in[2];   // [64]
    float* out = (float*)d_out;
    unsigned short* wre = (unsigned short*)d_ws;            // 512 KB (2 levels)
    float* part  = (float*)((char*)d_ws + PART_OFF);
    int*   histp = (int*)  ((char*)d_ws + HISTP_OFF);
    float* entp  = (float*)((char*)d_ws + ENTP_OFF);

    hipMemsetAsync(histp, 0, NHC * NE * sizeof(int), stream);

    prep_w   <<<dim3(256),        dim3(64),  0, stream>>>(w, wre);
    gemm_part<<<dim3(256 * NKQ),  dim3(256), 0, stream>>>(x, wre, part);
    epilogue <<<dim3(N_TOK / EB), dim3(256), 0, stream>>>(part, bias, out, histp, entp);
    finalize <<<dim3(1),          dim3(256), 0, stream>>>(histp, entp, out);
}

// Round 7
// 223.007 us; speedup vs baseline: 1.2137x; 1.0057x over previous
//
#include <hip/hip_runtime.h>
#include <math.h>

// Problem constants
#define N_TOK 16384
#define DDIM  2048
#define NE    64
#define TK    8
#define BT    64              // tokens per gemm block tile (4 waves x 16)
#define NKQ   4               // K-split factor
#define KQL   (DDIM / NKQ)    // 512 K per split
#define NSTEP (KQL / 32)      // 16 steps of 32 per split
#define EB    16              // tokens per epilogue block
#define NHC   32              // histogram partial copies

// Scaling keeps fp16 split residues normal; logits scaled by 2^17, unscaled
// exactly in the epilogue.
#define XSCALE 64.0f
#define WSCALE 2048.0f
#define LUNSCALE (1.0f / 131072.0f)

// Output layout (flat concat, all fp32)
constexpr size_t OFF_TOP  = 0;
constexpr size_t OFF_SC   = (size_t)N_TOK * TK;
constexpr size_t OFF_IDX  = OFF_SC + (size_t)N_TOK * NE;
constexpr size_t OFF_HIST = OFF_IDX + (size_t)N_TOK * TK;
constexpr size_t OFF_ENT  = OFF_HIST + NE;

#define WLVL (NE * DDIM)                  // 131072 f16 per split level
#define PART_OFF  (1u << 20)              // fp32 partials @ ws+1MB (16 MB)
#define HISTP_OFF (PART_OFF + (16u << 20))
#define ENTP_OFF  (HISTP_OFF + NHC * NE * 4)

typedef _Float16 f16x8 __attribute__((ext_vector_type(8)));
typedef float    f32x4 __attribute__((ext_vector_type(4)));

typedef const __attribute__((address_space(1))) unsigned int gu32;
typedef       __attribute__((address_space(3))) unsigned int lu32;

// 2-level fp16 split: v = h + m + r, |r| <= 2^-22 |v|. v - (float)h is exact.
__device__ __forceinline__ void split2(float v, _Float16& h, _Float16& m) {
    h = (_Float16)v;
    m = (_Float16)(v - (float)h);
}

__device__ __forceinline__ unsigned short f16bits(_Float16 h) {
    union { _Float16 f; unsigned short u; } c; c.f = h; return c.u;
}

// ---------------------------------------------------------------------------
// Prep: w*2048 -> 2-level fp16, swizzled B-fragment-linear:
// offset = ((s*4+nt)*64 + lane)*8 + j,  s=k/32, nt=e/16, lane=(k/8%4)*16+e%16
// ---------------------------------------------------------------------------
__global__ __launch_bounds__(64)
void prep_w(const float* __restrict__ w, unsigned short* __restrict__ wre) {
    int gid = blockIdx.x * 64 + threadIdx.x;   // 16384 threads, 8 elems each
    int e  = gid >> 8;
    int kb = gid & 255;
    int k  = kb * 8;
    const float* wp = w + (size_t)e * DDIM + k;
    float4 f0 = *(const float4*)(wp);
    float4 f1 = *(const float4*)(wp + 4);
    float av[8] = {f0.x, f0.y, f0.z, f0.w, f1.x, f1.y, f1.z, f1.w};

    int s = k >> 5, quad = kb & 3, nt = e >> 4, lane = quad * 16 + (e & 15);
    size_t off = ((size_t)(s * 4 + nt) * 64 + lane) * 8;

    unsigned short hb[8], mb[8];
    #pragma unroll
    for (int j = 0; j < 8; ++j) {
        _Float16 h, m;
        split2(av[j] * WSCALE, h, m);
        hb[j] = f16bits(h); mb[j] = f16bits(m);
    }

    #pragma unroll
    for (int lev = 0; lev < 2; ++lev) {
        const unsigned short* src = lev ? mb : hb;
        uint4 v;
        v.x = (unsigned)src[0] | ((unsigned)src[1] << 16);
        v.y = (unsigned)src[2] | ((unsigned)src[3] << 16);
        v.z = (unsigned)src[4] | ((unsigned)src[5] << 16);
        v.w = (unsigned)src[6] | ((unsigned)src[7] << 16);
        *(uint4*)(wre + (size_t)lev * WLVL + off) = v;
    }
}

// ---------------------------------------------------------------------------
// GEMM: K-split x4. B for 8 steps (64 KB) staged into LDS at once ->
// the 8-step inner loop has ZERO barriers (kills the per-step vmcnt(0)
// drain that capped round 6). 3 barriers total per kernel. A streamed from
// global with depth-2 prefetch that now genuinely stays in flight.
// 64 KB LDS -> 2 blocks/CU (8 waves/CU).
// ---------------------------------------------------------------------------
__global__ __launch_bounds__(256, 2)
void gemm_part(const float* __restrict__ x,
               const unsigned short* __restrict__ wre,
               float* __restrict__ part)
{
    // [step 0..7][frag = lev*4+nt][lane*8+j] : 64 KB
    __shared__ _Float16 Bs[8][8][512];

    const int bid  = blockIdx.x;
    const int tile = bid & 255;
    const int kq   = bid >> 8;          // 0..3
    const int tid  = threadIdx.x;
    const int lane = tid & 63;
    const int wid  = tid >> 6;
    const int t0b  = tile * BT;

    const int mrow = lane & 15;
    const int quad = lane >> 4;
    const float* xp = x + (size_t)(t0b + wid * 16 + mrow) * DDIM
                        + kq * KQL + quad * 8;

    // Stage chunk c (8 steps = 64 rows of 1 KB); wave wid stages 16 rows.
    auto stage = [&](int c) {
        #pragma unroll
        for (int i = 0; i < 16; ++i) {
            const int r = wid * 16 + i;            // 0..63
            const int s = r >> 3, f = r & 7, lev = f >> 2, nt = f & 3;
            const unsigned short* g = wre + (size_t)lev * WLVL
                + ((size_t)((kq * 2 + c) * 8 + s) * 4 + nt) * 512
                + (size_t)lane * 8;
            __builtin_amdgcn_global_load_lds((gu32*)g, (lu32*)&Bs[s][f][0],
                                             16, 0, 0);
        }
    };

    f32x4 acc[4];
    #pragma unroll
    for (int nt = 0; nt < 4; ++nt) acc[nt] = (f32x4){0.f, 0.f, 0.f, 0.f};

    // A prefetch ring, depth 2 (global step t = 0..15)
    float4 A0[2], A1[2];
    A0[0] = *(const float4*)(xp);      A1[0] = *(const float4*)(xp + 4);
    A0[1] = *(const float4*)(xp + 32); A1[1] = *(const float4*)(xp + 36);

    #pragma unroll
    for (int t = 0; t < NSTEP; ++t) {
        if ((t & 7) == 0) {
            if (t) __syncthreads();    // all reads of previous chunk done
            stage(t >> 3);
            __syncthreads();           // staging visible
        }
        const int s = t & 7;

        float4 ca = A0[t & 1], cb = A1[t & 1];
        if (t + 2 < NSTEP) {
            A0[t & 1] = *(const float4*)(xp + (t + 2) * 32);
            A1[t & 1] = *(const float4*)(xp + (t + 2) * 32 + 4);
        }

        // B fragments from LDS (shared by all 4 waves, conflict-free)
        f16x8 bh[4], bm[4];
        #pragma unroll
        for (int nt = 0; nt < 4; ++nt) {
            bh[nt] = *(const f16x8*)&Bs[s][nt][lane * 8];
            bm[nt] = *(const f16x8*)&Bs[s][4 + nt][lane * 8];
        }

        // Split current A (scaled) into 2-level fp16
        float av[8] = {ca.x, ca.y, ca.z, ca.w, cb.x, cb.y, cb.z, cb.w};
        f16x8 ah, am;
        #pragma unroll
        for (int j = 0; j < 8; ++j) {
            _Float16 h, m;
            split2(av[j] * XSCALE, h, m);
            ah[j] = h; am[j] = m;
        }

        #pragma unroll
        for (int nt = 0; nt < 4; ++nt) {
            acc[nt] = __builtin_amdgcn_mfma_f32_16x16x32_f16(ah, bh[nt], acc[nt], 0, 0, 0);
            acc[nt] = __builtin_amdgcn_mfma_f32_16x16x32_f16(am, bh[nt], acc[nt], 0, 0, 0);
            acc[nt] = __builtin_amdgcn_mfma_f32_16x16x32_f16(ah, bm[nt], acc[nt], 0, 0, 0);
            acc[nt] = __builtin_amdgcn_mfma_f32_16x16x32_f16(am, bm[nt], acc[nt], 0, 0, 0);
        }
    }

    // Store partials: C/D map col=lane&15 (expert), row=quad*4+r (token)
    #pragma unroll
    for (int nt = 0; nt < 4; ++nt) {
        const int e = nt * 16 + mrow;
        #pragma unroll
        for (int r = 0; r < 4; ++r) {
            const int tok = wid * 16 + quad * 4 + r;
            part[((size_t)kq * N_TOK + t0b + tok) * NE + e] = acc[nt][r];
        }
    }
}

// ---------------------------------------------------------------------------
// Epilogue: fp64-combine partials, unscale 2^-17, sigmoid, scores, top-8.
// Histogram -> banked int partials; entropy -> per-block partial. No float
// atomics (deterministic).
// ---------------------------------------------------------------------------
__global__ __launch_bounds__(256, 4)
void epilogue(const float* __restrict__ part,
              const float* __restrict__ bias,
              float* __restrict__ out,
              int* __restrict__ histp,
              float* __restrict__ entp)
{
    __shared__ float sct[NE][EB + 1];
    __shared__ float bs[NE];
    __shared__ int   hist[NE];

    const int tid = threadIdx.x;
    const int t0b = blockIdx.x * EB;

    if (tid < NE) { bs[tid] = bias[tid]; hist[tid] = 0; }

    {
        const int tok = tid >> 4;
        const int e   = (tid & 15) * 4;
        double d0 = 0, d1 = 0, d2 = 0, d3 = 0;
        #pragma unroll
        for (int kq = 0; kq < NKQ; ++kq) {
            float4 v = *(const float4*)&part[((size_t)kq * N_TOK + t0b + tok) * NE + e];
            d0 += v.x; d1 += v.y; d2 += v.z; d3 += v.w;
        }
        float4 sv;
        sv.x = 1.0f / (1.0f + expf(-(float)d0 * LUNSCALE));
        sv.y = 1.0f / (1.0f + expf(-(float)d1 * LUNSCALE));
        sv.z = 1.0f / (1.0f + expf(-(float)d2 * LUNSCALE));
        sv.w = 1.0f / (1.0f + expf(-(float)d3 * LUNSCALE));
        sct[e + 0][tok] = sv.x;
        sct[e + 1][tok] = sv.y;
        sct[e + 2][tok] = sv.z;
        sct[e + 3][tok] = sv.w;
        *(float4*)&out[OFF_SC + (size_t)(t0b + tok) * NE + e] = sv;
    }
    __syncthreads();

    float ent = 0.f;
    if (tid < EB) {
        const int t = tid;
        float v[NE];
        #pragma unroll
        for (int e = 0; e < NE; ++e) v[e] = sct[e][t] + bs[e];

        float chosen[TK];
        int   cidx[TK];
        float ssum = 0.f;
        #pragma unroll
        for (int p = 0; p < TK; ++p) {
            float best = v[0];
            int   bi   = 0;
            #pragma unroll
            for (int e = 1; e < NE; ++e) {   // strict '>' => lowest index on tie
                bool sel = v[e] > best;
                best = sel ? v[e] : best;
                bi   = sel ? e : bi;
            }
            #pragma unroll
            for (int e = 0; e < NE; ++e) v[e] = (e == bi) ? -1e30f : v[e];
            float sc = sct[bi][t];
            chosen[p] = sc;
            cidx[p]   = bi;
            ssum += sc;
            atomicAdd(&hist[bi], 1);        // LDS atomic
        }

        const float inv = 1.0f / (ssum + 1e-20f);
        #pragma unroll
        for (int p = 0; p < TK; ++p) {
            float pn = chosen[p] * inv;      // ROUTE_SCALE == 1.0
            out[OFF_TOP + (size_t)(t0b + t) * TK + p] = pn;
            out[OFF_IDX + (size_t)(t0b + t) * TK + p] = (float)cidx[p];
            ent += pn * logf(pn);
        }
    }
    if (tid < 64) {
        #pragma unroll
        for (int o = 32; o > 0; o >>= 1) ent += __shfl_down(ent, o);
        if (tid == 0) entp[blockIdx.x] = ent;
    }
    __syncthreads();

    if (tid < NE && hist[tid] > 0)
        atomicAdd(&histp[(blockIdx.x & (NHC - 1)) * NE + tid], hist[tid]);
}

// ---------------------------------------------------------------------------
// Finalize: reduce histogram banks and entropy partials (deterministic)
// ---------------------------------------------------------------------------
__global__ __launch_bounds__(256)
void finalize(const int* __restrict__ histp,
              const float* __restrict__ entp,
              float* __restrict__ out)
{
    const int tid = threadIdx.x;
    if (tid < NE) {
        int s = 0;
        #pragma unroll
        for (int c = 0; c < NHC; ++c) s += histp[c * NE + tid];
        out[OFF_HIST + tid] = (float)s;
    }
    __shared__ float red[256];
    float e = 0.f;
    for (int i = tid; i < N_TOK / EB; i += 256) e += entp[i];
    red[tid] = e;
    __syncthreads();
    #pragma unroll
    for (int o = 128; o > 0; o >>= 1) {
        if (tid < o) red[tid] += red[tid + o];
        __syncthreads();
    }
    if (tid == 0) out[OFF_ENT] = -red[0] * (1.0f / (float)N_TOK);
}

extern "C" void kernel_launch(void* const* d_in, const int* in_sizes, int n_in,
                              void* d_out, int out_size, void* d_ws, size_t ws_size,
                              hipStream_t stream) {
    const float* x    = (const float*)d_in[0];   // [16384, 2048]
    const float* w    = (const float*)d_in[1];   // [64, 2048]
    const float* bias = (const float*)d_in[2];   // [64]
    float* out = (float*)d_out;
    unsigned short* wre = (unsigned short*)d_ws;            // 512 KB (2 levels)
    float* part  = (float*)((char*)d_ws + PART_OFF);
    int*   histp = (int*)  ((char*)d_ws + HISTP_OFF);
    float* entp  = (float*)((char*)d_ws + ENTP_OFF);

    hipMemsetAsync(histp, 0, NHC * NE * sizeof(int), stream);

    prep_w   <<<dim3(256),        dim3(64),  0, stream>>>(w, wre);
    gemm_part<<<dim3(256 * NKQ),  dim3(256), 0, stream>>>(x, wre, part);
    epilogue <<<dim3(N_TOK / EB), dim3(256), 0, stream>>>(part, bias, out, histp, entp);
    finalize <<<dim3(1),          dim3(256), 0, stream>>>(histp, entp, out);
}